// Round 1
// baseline (583.934 us; speedup 1.0000x reference)
//
#include <hip/hip_runtime.h>
#include <hip/hip_bf16.h>
#include <cstdint>
#include <cstddef>

// Problem constants
#define Bb 4
#define Ss 2048
#define Dd 1024
#define Hh 16
#define DKk 64
#define Mm (Bb*Ss)   // 8192 rows

typedef __bf16 bf16_t;
typedef __bf16 bf16x8 __attribute__((ext_vector_type(8)));
typedef float  f32x4  __attribute__((ext_vector_type(4)));
typedef unsigned int u32x4 __attribute__((ext_vector_type(4)));

#define MFMA16(a,b,c) __builtin_amdgcn_mfma_f32_16x16x32_bf16(a,b,c,0,0,0)

static __device__ __forceinline__ bf16x8 ld16g(const bf16_t* p) {
  return __builtin_bit_cast(bf16x8, *reinterpret_cast<const u32x4*>(p));
}

static __device__ __forceinline__ void gload_lds16(const bf16_t* g, bf16_t* l) {
  __builtin_amdgcn_global_load_lds(
      (__attribute__((address_space(1))) void*)(g),
      (__attribute__((address_space(3))) void*)(l),
      16, 0, 0);
}

// ---------------- fp32 -> bf16 convert (vectorized x4) ----------------
__global__ void cvt_f32_bf16(const float* __restrict__ in, bf16_t* __restrict__ out) {
  int i = (blockIdx.x * blockDim.x + threadIdx.x) * 4;
  float4 f = *reinterpret_cast<const float4*>(in + i);
  out[i + 0] = (bf16_t)f.x;
  out[i + 1] = (bf16_t)f.y;
  out[i + 2] = (bf16_t)f.z;
  out[i + 3] = (bf16_t)f.w;
}

// ---------------- GEMM: C[m][n] = sum_k A[m][k] * B[n][k] ----------------
// 128x128 tile, BK=32, 4 waves (2x2), each wave 64x64 (4x4 of 16x16 frags).
template <typename OutT>
__global__ __launch_bounds__(256) void gemm_bt(const bf16_t* __restrict__ A,
                                               const bf16_t* __restrict__ Bm,
                                               OutT* __restrict__ C,
                                               int Kdim, int Ndim) {
  __shared__ bf16_t As[2][128 * 32];
  __shared__ bf16_t Bs[2][128 * 32];
  const int t = threadIdx.x;
  const int lane = t & 63, w = t >> 6;
  const int l15 = lane & 15, lg = lane >> 4;
  const int m0 = blockIdx.x * 128, n0 = blockIdx.y * 128;
  const int wr = w >> 1, wc = w & 1;

  f32x4 acc[4][4] = {};

  auto stage = [&](int buf, int kt) {
    const int k0 = kt * 32;
#pragma unroll
    for (int c = 0; c < 2; ++c) {
      int flat = (c * 256 + t) * 16;    // byte offset in 8KB tile
      int row = flat >> 6;              // 64B per row (32 bf16)
      int ke = (flat & 63) >> 1;        // element offset within row
      const bf16_t* ga = A  + (size_t)(m0 + row) * Kdim + k0 + ke;
      const bf16_t* gb = Bm + (size_t)(n0 + row) * Kdim + k0 + ke;
      // wave-uniform LDS base (HW adds lane*16)
      bf16_t* la = &As[buf][c * 2048 + w * 512];
      bf16_t* lb = &Bs[buf][c * 2048 + w * 512];
      gload_lds16(ga, la);
      gload_lds16(gb, lb);
    }
  };

  const int KT = Kdim / 32;
  stage(0, 0);
  __syncthreads();
  int buf = 0;
  for (int kt = 0; kt < KT; ++kt) {
    if (kt + 1 < KT) stage(buf ^ 1, kt + 1);
    bf16x8 af[4], bfr[4];
#pragma unroll
    for (int i = 0; i < 4; ++i) {
      af[i]  = __builtin_bit_cast(bf16x8, *reinterpret_cast<const u32x4*>(
                  &As[buf][(wr * 64 + i * 16 + l15) * 32 + lg * 8]));
      bfr[i] = __builtin_bit_cast(bf16x8, *reinterpret_cast<const u32x4*>(
                  &Bs[buf][(wc * 64 + i * 16 + l15) * 32 + lg * 8]));
    }
#pragma unroll
    for (int i = 0; i < 4; ++i)
#pragma unroll
      for (int j = 0; j < 4; ++j)
        acc[i][j] = MFMA16(af[i], bfr[j], acc[i][j]);
    __syncthreads();
    buf ^= 1;
  }

  // epilogue: C/D layout col=lane&15, row=(lane>>4)*4+r
#pragma unroll
  for (int i = 0; i < 4; ++i) {
    int rowb = m0 + wr * 64 + i * 16 + lg * 4;
#pragma unroll
    for (int j = 0; j < 4; ++j) {
      int col = n0 + wc * 64 + j * 16 + l15;
#pragma unroll
      for (int r = 0; r < 4; ++r)
        C[(size_t)(rowb + r) * Ndim + col] = (OutT)acc[i][j][r];
    }
  }
}

// ---------------- RoPE (in-place, [B,S,H,64] bf16) ----------------
__global__ void rope_k(bf16_t* __restrict__ q) {
  int idx = blockIdx.x * blockDim.x + threadIdx.x;  // one per (b,s,h,i) pair
  int i = idx & 31;
  int s = (idx >> 9) & (Ss - 1);
  // 10000^(-i/32) = exp2(-i * log2(10000)/32)
  float inv_freq = exp2f(-(float)i * (13.2877123795494f / 32.0f));
  float ang = (float)s * inv_freq;
  float sn, cs;
  sincosf(ang, &sn, &cs);
  bf16_t* p = q + (size_t)idx * 2;
  float x1 = (float)p[0], x2 = (float)p[1];
  p[0] = (bf16_t)(cs * x1 - sn * x2);
  p[1] = (bf16_t)(sn * x1 + cs * x2);
}

// ---------------- V transpose: [B,S,H,64] -> [B,H,64,S] ----------------
__global__ __launch_bounds__(256) void transpose_v(const bf16_t* __restrict__ V,
                                                   bf16_t* __restrict__ Vt) {
  __shared__ bf16_t tile[64][72];  // padded rows, 144B (16B aligned)
  int bh = blockIdx.y;
  int b = bh >> 4, h = bh & 15;
  int s0 = blockIdx.x * 64;
  int t = threadIdx.x;
  const bf16_t* vbase = V + (size_t)b * Ss * Dd + h * 64;
#pragma unroll
  for (int c = 0; c < 2; ++c) {
    int cf = c * 256 + t;
    int s = cf >> 3, d8 = cf & 7;
    u32x4 v = *reinterpret_cast<const u32x4*>(vbase + (size_t)(s0 + s) * Dd + d8 * 8);
    *reinterpret_cast<u32x4*>(&tile[s][d8 * 8]) = v;
  }
  __syncthreads();
  bf16_t* obase = Vt + (size_t)bh * 64 * Ss;
#pragma unroll
  for (int c = 0; c < 2; ++c) {
    int cf = c * 256 + t;
    int d = cf >> 3, s8 = cf & 7;
    __align__(16) bf16_t tmp[8];
#pragma unroll
    for (int i = 0; i < 8; ++i) tmp[i] = tile[s8 * 8 + i][d];
    *reinterpret_cast<u32x4*>(obase + (size_t)d * Ss + s0 + s8 * 8) =
        *reinterpret_cast<const u32x4*>(tmp);
  }
}

// ---------------- Flash attention (causal) ----------------
// grid (S/64, B*H), 256 thr = 4 waves; wave handles 16 q-rows; 32-key tiles.
__global__ __launch_bounds__(256) void attn_k(const bf16_t* __restrict__ Q,
                                              const bf16_t* __restrict__ K,
                                              const bf16_t* __restrict__ Vt,
                                              bf16_t* __restrict__ O) {
  __shared__ __align__(16) bf16_t Plds[4][16 * 40];  // per-wave, stride 40 elems
  int t = threadIdx.x, lane = t & 63, w = t >> 6;
  int l15 = lane & 15, lg = lane >> 4;
  int bh = blockIdx.y, b = bh >> 4, h = bh & 15;
  int q0 = blockIdx.x * 64 + w * 16;
  const bf16_t* qb = Q + (size_t)b * Ss * Dd + h * 64;
  const bf16_t* kb = K + (size_t)b * Ss * Dd + h * 64;
  const bf16_t* vtb = Vt + (size_t)bh * 64 * Ss;

  bf16x8 aq0 = ld16g(qb + (size_t)(q0 + l15) * Dd + lg * 8);
  bf16x8 aq1 = ld16g(qb + (size_t)(q0 + l15) * Dd + 32 + lg * 8);

  float m_r[4], l_r[4];
  f32x4 o_[4];
#pragma unroll
  for (int r = 0; r < 4; ++r) { m_r[r] = -INFINITY; l_r[r] = 0.f; }
#pragma unroll
  for (int d = 0; d < 4; ++d) o_[d] = f32x4{0.f, 0.f, 0.f, 0.f};

  const int ktiles = (q0 + 15) / 32 + 1;
  for (int kt = 0; kt < ktiles; ++kt) {
    const int kbase = kt * 32;
    bf16x8 bk00 = ld16g(kb + (size_t)(kbase + l15) * Dd + lg * 8);
    bf16x8 bk01 = ld16g(kb + (size_t)(kbase + l15) * Dd + 32 + lg * 8);
    bf16x8 bk10 = ld16g(kb + (size_t)(kbase + 16 + l15) * Dd + lg * 8);
    bf16x8 bk11 = ld16g(kb + (size_t)(kbase + 16 + l15) * Dd + 32 + lg * 8);
    f32x4 s0 = {0.f, 0.f, 0.f, 0.f}, s1 = {0.f, 0.f, 0.f, 0.f};
    s0 = MFMA16(aq0, bk00, s0);
    s0 = MFMA16(aq1, bk01, s0);
    s1 = MFMA16(aq0, bk10, s1);
    s1 = MFMA16(aq1, bk11, s1);

    int key0 = kbase + l15, key1 = kbase + 16 + l15;
    float pm0[4], pm1[4];
#pragma unroll
    for (int r = 0; r < 4; ++r) {
      int qrow = q0 + lg * 4 + r;
      float v0 = (key0 <= qrow) ? s0[r] * 0.125f : -INFINITY;
      float v1 = (key1 <= qrow) ? s1[r] * 0.125f : -INFINITY;
      float mx = fmaxf(v0, v1);
#pragma unroll
      for (int off = 1; off < 16; off <<= 1) mx = fmaxf(mx, __shfl_xor(mx, off));
      float mnew = fmaxf(m_r[r], mx);
      float alpha = __expf(m_r[r] - mnew);
      float p0 = __expf(v0 - mnew);
      float p1 = __expf(v1 - mnew);
      float sum = p0 + p1;
#pragma unroll
      for (int off = 1; off < 16; off <<= 1) sum += __shfl_xor(sum, off);
      l_r[r] = l_r[r] * alpha + sum;
      m_r[r] = mnew;
#pragma unroll
      for (int d = 0; d < 4; ++d) o_[d][r] *= alpha;
      pm0[r] = p0; pm1[r] = p1;
    }
    // P (D-layout) -> LDS -> A-layout
#pragma unroll
    for (int r = 0; r < 4; ++r) {
      int qrl = lg * 4 + r;
      Plds[w][qrl * 40 + l15]      = (bf16_t)pm0[r];
      Plds[w][qrl * 40 + 16 + l15] = (bf16_t)pm1[r];
    }
    asm volatile("s_waitcnt lgkmcnt(0)" ::: "memory");
    bf16x8 pa = __builtin_bit_cast(bf16x8, *reinterpret_cast<const u32x4*>(
        &Plds[w][l15 * 40 + lg * 8]));
#pragma unroll
    for (int d = 0; d < 4; ++d) {
      bf16x8 bv = ld16g(vtb + (size_t)(d * 16 + l15) * Ss + kbase + lg * 8);
      o_[d] = MFMA16(pa, bv, o_[d]);
    }
  }

#pragma unroll
  for (int r = 0; r < 4; ++r) {
    int qrow = q0 + lg * 4 + r;
    float inv = 1.0f / l_r[r];
#pragma unroll
    for (int d = 0; d < 4; ++d)
      O[((size_t)b * Ss + qrow) * Dd + h * 64 + d * 16 + l15] =
          (bf16_t)(o_[d][r] * inv);
  }
}

// ---------------- launcher ----------------
extern "C" void kernel_launch(void* const* d_in, const int* in_sizes, int n_in,
                              void* d_out, int out_size, void* d_ws, size_t ws_size,
                              hipStream_t stream) {
  (void)in_sizes; (void)n_in; (void)out_size; (void)ws_size;
  const float* x  = (const float*)d_in[0];
  const float* wq = (const float*)d_in[1];
  const float* wk = (const float*)d_in[2];
  const float* wv = (const float*)d_in[3];
  const float* wo = (const float*)d_in[4];
  float* out = (float*)d_out;

  char* ws = (char*)d_ws;
  const size_t MB16 = 16u << 20;
  bf16_t* xb  = (bf16_t*)(ws + 0);           // x bf16; later reused as Vt
  bf16_t* Qb  = (bf16_t*)(ws + 1 * MB16);
  bf16_t* Kb  = (bf16_t*)(ws + 2 * MB16);
  bf16_t* Vb  = (bf16_t*)(ws + 3 * MB16);    // V; later reused as attn-out
  bf16_t* wqb = (bf16_t*)(ws + 4 * MB16);
  bf16_t* wkb = (bf16_t*)(ws + 4 * MB16 + (2u << 20));
  bf16_t* wvb = (bf16_t*)(ws + 4 * MB16 + (4u << 20));
  bf16_t* wob = (bf16_t*)(ws + 4 * MB16 + (6u << 20));
  bf16_t* Vt  = xb;   // alias: x dead after projections
  bf16_t* AOb = Vb;   // alias: V dead after transpose

  // 1. converts
  cvt_f32_bf16<<<(Mm * Dd) / 1024, 256, 0, stream>>>(x, xb);
  cvt_f32_bf16<<<(Dd * Dd) / 1024, 256, 0, stream>>>(wq, wqb);
  cvt_f32_bf16<<<(Dd * Dd) / 1024, 256, 0, stream>>>(wk, wkb);
  cvt_f32_bf16<<<(Dd * Dd) / 1024, 256, 0, stream>>>(wv, wvb);
  cvt_f32_bf16<<<(Dd * Dd) / 1024, 256, 0, stream>>>(wo, wob);

  // 2. projections: Q/K/V = x @ w^T
  dim3 gg(Mm / 128, Dd / 128);
  gemm_bt<bf16_t><<<gg, 256, 0, stream>>>(xb, wqb, Qb, Dd, Dd);
  gemm_bt<bf16_t><<<gg, 256, 0, stream>>>(xb, wkb, Kb, Dd, Dd);
  gemm_bt<bf16_t><<<gg, 256, 0, stream>>>(xb, wvb, Vb, Dd, Dd);

  // 3. RoPE on Q and K
  rope_k<<<(Bb * Ss * Hh * 32) / 256, 256, 0, stream>>>(Qb);
  rope_k<<<(Bb * Ss * Hh * 32) / 256, 256, 0, stream>>>(Kb);

  // 4. V transpose -> [B,H,64,S]
  transpose_v<<<dim3(Ss / 64, Bb * Hh), 256, 0, stream>>>(Vb, Vt);

  // 5. causal flash attention -> [B,S,D] bf16
  attn_k<<<dim3(Ss / 64, Bb * Hh), 256, 0, stream>>>(Qb, Kb, Vt, AOb);

  // 6. output projection (fp32 out)
  gemm_bt<float><<<gg, 256, 0, stream>>>(AOb, wob, out, Dd, Dd);
}

// Round 2
// 363.335 us; speedup vs baseline: 1.6071x; 1.6071x over previous
//
#include <hip/hip_runtime.h>
#include <hip/hip_bf16.h>
#include <cstdint>
#include <cstddef>

// Problem constants
#define Bb 4
#define Ss 2048
#define Dd 1024
#define Hh 16
#define DKk 64
#define Mm (Bb*Ss)   // 8192 rows

typedef __bf16 bf16_t;
typedef __bf16 bf16x8 __attribute__((ext_vector_type(8)));
typedef __bf16 bf16x4 __attribute__((ext_vector_type(4)));
typedef float  f32x4  __attribute__((ext_vector_type(4)));
typedef unsigned int u32x4 __attribute__((ext_vector_type(4)));
typedef unsigned int u32x2 __attribute__((ext_vector_type(2)));

#define MFMA16(a,b,c) __builtin_amdgcn_mfma_f32_16x16x32_bf16(a,b,c,0,0,0)

static __device__ __forceinline__ bf16x8 ld16g(const bf16_t* p) {
  return __builtin_bit_cast(bf16x8, *reinterpret_cast<const u32x4*>(p));
}

static __device__ __forceinline__ void gload_lds16(const bf16_t* g, bf16_t* l) {
  __builtin_amdgcn_global_load_lds(
      (__attribute__((address_space(1))) void*)(g),
      (__attribute__((address_space(3))) void*)(l),
      16, 0, 0);
}

// ---------------- fp32 -> bf16 convert (vectorized x4) ----------------
__global__ void cvt_f32_bf16(const float* __restrict__ in, bf16_t* __restrict__ out) {
  int i = (blockIdx.x * blockDim.x + threadIdx.x) * 4;
  float4 f = *reinterpret_cast<const float4*>(in + i);
  out[i + 0] = (bf16_t)f.x;
  out[i + 1] = (bf16_t)f.y;
  out[i + 2] = (bf16_t)f.z;
  out[i + 3] = (bf16_t)f.w;
}

// ---------------- GEMM: C[m][n] = sum_k A[m][k] * B[n][k] ----------------
// 128x128 tile, BK=32, 4 waves (2x2), each wave 64x64 (4x4 of 16x16 frags).
template <typename OutT>
__global__ __launch_bounds__(256) void gemm_bt(const bf16_t* __restrict__ A,
                                               const bf16_t* __restrict__ Bm,
                                               OutT* __restrict__ C,
                                               int Kdim, int Ndim) {
  __shared__ bf16_t As[2][128 * 32];
  __shared__ bf16_t Bs[2][128 * 32];
  const int t = threadIdx.x;
  const int lane = t & 63, w = t >> 6;
  const int l15 = lane & 15, lg = lane >> 4;
  const int m0 = blockIdx.x * 128, n0 = blockIdx.y * 128;
  const int wr = w >> 1, wc = w & 1;

  f32x4 acc[4][4] = {};

  auto stage = [&](int buf, int kt) {
    const int k0 = kt * 32;
#pragma unroll
    for (int c = 0; c < 2; ++c) {
      int flat = (c * 256 + t) * 16;    // byte offset in 8KB tile
      int row = flat >> 6;              // 64B per row (32 bf16)
      int ke = (flat & 63) >> 1;        // element offset within row
      const bf16_t* ga = A  + (size_t)(m0 + row) * Kdim + k0 + ke;
      const bf16_t* gb = Bm + (size_t)(n0 + row) * Kdim + k0 + ke;
      // wave-uniform LDS base (HW adds lane*16)
      bf16_t* la = &As[buf][c * 2048 + w * 512];
      bf16_t* lb = &Bs[buf][c * 2048 + w * 512];
      gload_lds16(ga, la);
      gload_lds16(gb, lb);
    }
  };

  const int KT = Kdim / 32;
  stage(0, 0);
  __syncthreads();
  int buf = 0;
  for (int kt = 0; kt < KT; ++kt) {
    if (kt + 1 < KT) stage(buf ^ 1, kt + 1);
    bf16x8 af[4], bfr[4];
#pragma unroll
    for (int i = 0; i < 4; ++i) {
      af[i]  = __builtin_bit_cast(bf16x8, *reinterpret_cast<const u32x4*>(
                  &As[buf][(wr * 64 + i * 16 + l15) * 32 + lg * 8]));
      bfr[i] = __builtin_bit_cast(bf16x8, *reinterpret_cast<const u32x4*>(
                  &Bs[buf][(wc * 64 + i * 16 + l15) * 32 + lg * 8]));
    }
#pragma unroll
    for (int i = 0; i < 4; ++i)
#pragma unroll
      for (int j = 0; j < 4; ++j)
        acc[i][j] = MFMA16(af[i], bfr[j], acc[i][j]);
    __syncthreads();
    buf ^= 1;
  }

  // epilogue: C/D layout col=lane&15, row=(lane>>4)*4+r
#pragma unroll
  for (int i = 0; i < 4; ++i) {
    int rowb = m0 + wr * 64 + i * 16 + lg * 4;
#pragma unroll
    for (int j = 0; j < 4; ++j) {
      int col = n0 + wc * 64 + j * 16 + l15;
#pragma unroll
      for (int r = 0; r < 4; ++r)
        C[(size_t)(rowb + r) * Ndim + col] = (OutT)acc[i][j][r];
    }
  }
}

// ---------------- RoPE (in-place, [B,S,H,64] bf16) ----------------
__global__ void rope_k(bf16_t* __restrict__ q) {
  int idx = blockIdx.x * blockDim.x + threadIdx.x;  // one per (b,s,h,i) pair
  int i = idx & 31;
  int s = (idx >> 9) & (Ss - 1);
  // 10000^(-i/32) = exp2(-i * log2(10000)/32)
  float inv_freq = exp2f(-(float)i * (13.2877123795494f / 32.0f));
  float ang = (float)s * inv_freq;
  float sn, cs;
  sincosf(ang, &sn, &cs);
  bf16_t* p = q + (size_t)idx * 2;
  float x1 = (float)p[0], x2 = (float)p[1];
  p[0] = (bf16_t)(cs * x1 - sn * x2);
  p[1] = (bf16_t)(sn * x1 + cs * x2);
}

// ---------------- V transpose: [B,S,H,64] -> [B,H,64,S] ----------------
__global__ __launch_bounds__(256) void transpose_v(const bf16_t* __restrict__ V,
                                                   bf16_t* __restrict__ Vt) {
  __shared__ bf16_t tile[64][72];  // padded rows, 144B (16B aligned)
  int bh = blockIdx.y;
  int b = bh >> 4, h = bh & 15;
  int s0 = blockIdx.x * 64;
  int t = threadIdx.x;
  const bf16_t* vbase = V + (size_t)b * Ss * Dd + h * 64;
#pragma unroll
  for (int c = 0; c < 2; ++c) {
    int cf = c * 256 + t;
    int s = cf >> 3, d8 = cf & 7;
    u32x4 v = *reinterpret_cast<const u32x4*>(vbase + (size_t)(s0 + s) * Dd + d8 * 8);
    *reinterpret_cast<u32x4*>(&tile[s][d8 * 8]) = v;
  }
  __syncthreads();
  bf16_t* obase = Vt + (size_t)bh * 64 * Ss;
#pragma unroll
  for (int c = 0; c < 2; ++c) {
    int cf = c * 256 + t;
    int d = cf >> 3, s8 = cf & 7;
    __align__(16) bf16_t tmp[8];
#pragma unroll
    for (int i = 0; i < 8; ++i) tmp[i] = tile[s8 * 8 + i][d];
    *reinterpret_cast<u32x4*>(obase + (size_t)d * Ss + s0 + s8 * 8) =
        *reinterpret_cast<const u32x4*>(tmp);
  }
}

// ---------------- Flash attention (causal, swapped-QK^T, balanced pairs) --
// grid (16, B*H), 256 thr = 4 waves. Wave i = blk*4+w handles TWO 16-row
// q-chunks: q0a = 16*i (early) and q0b = 2032-16*i (late) -> every wave does
// ~65 k-tiles (balanced). Swapped QK^T: S^T = mfma(K_frag, Q_frag) puts
// q-row = lane&15 (one row per lane) -> softmax stats are per-lane scalars,
// row-reduce = 2 shfl_xor. PV as O^T = mfma(Vt_frag, P_frag): alpha-rescale
// and 1/l finalize are lane-local. K/V fragment loads shared by both chains.
__global__ __launch_bounds__(256) void attn_k(const bf16_t* __restrict__ Q,
                                              const bf16_t* __restrict__ K,
                                              const bf16_t* __restrict__ Vt,
                                              bf16_t* __restrict__ O) {
  __shared__ __align__(16) bf16_t Plds[4][2][16 * 40];  // [wave][chain], stride 40
  const int t = threadIdx.x, lane = t & 63, w = t >> 6;
  const int l15 = lane & 15, lg = lane >> 4;
  const int bh = blockIdx.y, b = bh >> 4, h = bh & 15;
  const int i = blockIdx.x * 4 + w;
  const int q0[2] = {16 * i, 2032 - 16 * i};
  const bf16_t* qb = Q + (size_t)b * Ss * Dd + h * 64;
  const bf16_t* kb = K + (size_t)b * Ss * Dd + h * 64;
  const bf16_t* vtb = Vt + (size_t)bh * 64 * Ss;

  bf16x8 qf[2][2];
#pragma unroll
  for (int ch = 0; ch < 2; ++ch)
#pragma unroll
    for (int c = 0; c < 2; ++c)
      qf[ch][c] = ld16g(qb + (size_t)(q0[ch] + l15) * Dd + c * 32 + lg * 8);

  float m_[2] = {-INFINITY, -INFINITY};
  float l_[2] = {0.f, 0.f};
  f32x4 o_[2][4] = {};
  const int kta0 = q0[0] / 32 + 1;
  const int ktb  = q0[1] / 32 + 1;

  for (int kt = 0; kt < ktb; ++kt) {
    const int kbase = kt * 32;
    // shared K/V fragment loads for both chains
    bf16x8 kf[2][2], vf[4];
#pragma unroll
    for (int tt = 0; tt < 2; ++tt)
#pragma unroll
      for (int c = 0; c < 2; ++c)
        kf[tt][c] = ld16g(kb + (size_t)(kbase + 16 * tt + l15) * Dd + c * 32 + lg * 8);
#pragma unroll
    for (int dg = 0; dg < 4; ++dg)
      vf[dg] = ld16g(vtb + (size_t)(dg * 16 + l15) * Ss + kbase + lg * 8);

    const bool act0 = (kt < kta0);
    f32x4 sc[2][2];
    // QK^T (swapped): sc[ch][tt] = S^T rows kbase+16tt.. , col = q-row l15
#pragma unroll
    for (int ch = 0; ch < 2; ++ch) {
      if (ch == 0 && !act0) continue;
      f32x4 s0 = {0.f, 0.f, 0.f, 0.f}, s1 = {0.f, 0.f, 0.f, 0.f};
      s0 = MFMA16(kf[0][0], qf[ch][0], s0);
      s0 = MFMA16(kf[0][1], qf[ch][1], s0);
      s1 = MFMA16(kf[1][0], qf[ch][0], s1);
      s1 = MFMA16(kf[1][1], qf[ch][1], s1);
      sc[ch][0] = s0; sc[ch][1] = s1;
    }
    // online softmax, per-lane scalar stats (q-row = q0+l15)
#pragma unroll
    for (int ch = 0; ch < 2; ++ch) {
      if (ch == 0 && !act0) continue;
      const int qrow = q0[ch] + l15;
      float v[2][4];
      float mx = -INFINITY;
#pragma unroll
      for (int tt = 0; tt < 2; ++tt)
#pragma unroll
        for (int r = 0; r < 4; ++r) {
          int key = kbase + 16 * tt + lg * 4 + r;
          float x = (key <= qrow) ? sc[ch][tt][r] * 0.125f : -INFINITY;
          v[tt][r] = x;
          mx = fmaxf(mx, x);
        }
      mx = fmaxf(mx, __shfl_xor(mx, 16));
      mx = fmaxf(mx, __shfl_xor(mx, 32));
      const float mnew = fmaxf(m_[ch], mx);
      const float alpha = __expf(m_[ch] - mnew);
      m_[ch] = mnew;
      float sum = 0.f;
      bf16x4 pk0, pk1;
#pragma unroll
      for (int r = 0; r < 4; ++r) {
        float p0 = __expf(v[0][r] - mnew);
        float p1 = __expf(v[1][r] - mnew);
        sum += p0 + p1;
        pk0[r] = (bf16_t)p0;
        pk1[r] = (bf16_t)p1;
      }
      sum += __shfl_xor(sum, 16);
      sum += __shfl_xor(sum, 32);
      l_[ch] = l_[ch] * alpha + sum;
#pragma unroll
      for (int dg = 0; dg < 4; ++dg) o_[ch][dg] *= alpha;
      // P[q][k] row-major into LDS (q = l15, keys 16tt+lg*4+r)
      *reinterpret_cast<u32x2*>(&Plds[w][ch][l15 * 40 + lg * 4]) =
          __builtin_bit_cast(u32x2, pk0);
      *reinterpret_cast<u32x2*>(&Plds[w][ch][l15 * 40 + 16 + lg * 4]) =
          __builtin_bit_cast(u32x2, pk1);
    }
    asm volatile("s_waitcnt lgkmcnt(0)" ::: "memory");
    __builtin_amdgcn_sched_barrier(0);
    // PV: O^T = mfma(Vt_frag, P_frag) -> o rows d=lg*4+r, col q=l15
#pragma unroll
    for (int ch = 0; ch < 2; ++ch) {
      if (ch == 0 && !act0) continue;
      bf16x8 pb = __builtin_bit_cast(bf16x8, *reinterpret_cast<const u32x4*>(
          &Plds[w][ch][l15 * 40 + lg * 8]));
#pragma unroll
      for (int dg = 0; dg < 4; ++dg)
        o_[ch][dg] = MFMA16(vf[dg], pb, o_[ch][dg]);
    }
  }

  // epilogue: row q0+l15, cols h*64 + dg*16 + lg*4 + r
#pragma unroll
  for (int ch = 0; ch < 2; ++ch) {
    const float inv = 1.0f / l_[ch];
    const size_t rowoff = ((size_t)b * Ss + q0[ch] + l15) * Dd + h * 64;
#pragma unroll
    for (int dg = 0; dg < 4; ++dg) {
      bf16x4 ov;
#pragma unroll
      for (int r = 0; r < 4; ++r) ov[r] = (bf16_t)(o_[ch][dg][r] * inv);
      *reinterpret_cast<u32x2*>(&O[rowoff + dg * 16 + lg * 4]) =
          __builtin_bit_cast(u32x2, ov);
    }
  }
}

// ---------------- launcher ----------------
extern "C" void kernel_launch(void* const* d_in, const int* in_sizes, int n_in,
                              void* d_out, int out_size, void* d_ws, size_t ws_size,
                              hipStream_t stream) {
  (void)in_sizes; (void)n_in; (void)out_size; (void)ws_size;
  const float* x  = (const float*)d_in[0];
  const float* wq = (const float*)d_in[1];
  const float* wk = (const float*)d_in[2];
  const float* wv = (const float*)d_in[3];
  const float* wo = (const float*)d_in[4];
  float* out = (float*)d_out;

  char* ws = (char*)d_ws;
  const size_t MB16 = 16u << 20;
  bf16_t* xb  = (bf16_t*)(ws + 0);           // x bf16; later reused as Vt
  bf16_t* Qb  = (bf16_t*)(ws + 1 * MB16);
  bf16_t* Kb  = (bf16_t*)(ws + 2 * MB16);
  bf16_t* Vb  = (bf16_t*)(ws + 3 * MB16);    // V; later reused as attn-out
  bf16_t* wqb = (bf16_t*)(ws + 4 * MB16);
  bf16_t* wkb = (bf16_t*)(ws + 4 * MB16 + (2u << 20));
  bf16_t* wvb = (bf16_t*)(ws + 4 * MB16 + (4u << 20));
  bf16_t* wob = (bf16_t*)(ws + 4 * MB16 + (6u << 20));
  bf16_t* Vt  = xb;   // alias: x dead after projections
  bf16_t* AOb = Vb;   // alias: V dead after transpose

  // 1. converts
  cvt_f32_bf16<<<(Mm * Dd) / 1024, 256, 0, stream>>>(x, xb);
  cvt_f32_bf16<<<(Dd * Dd) / 1024, 256, 0, stream>>>(wq, wqb);
  cvt_f32_bf16<<<(Dd * Dd) / 1024, 256, 0, stream>>>(wk, wkb);
  cvt_f32_bf16<<<(Dd * Dd) / 1024, 256, 0, stream>>>(wv, wvb);
  cvt_f32_bf16<<<(Dd * Dd) / 1024, 256, 0, stream>>>(wo, wob);

  // 2. projections: Q/K/V = x @ w^T
  dim3 gg(Mm / 128, Dd / 128);
  gemm_bt<bf16_t><<<gg, 256, 0, stream>>>(xb, wqb, Qb, Dd, Dd);
  gemm_bt<bf16_t><<<gg, 256, 0, stream>>>(xb, wkb, Kb, Dd, Dd);
  gemm_bt<bf16_t><<<gg, 256, 0, stream>>>(xb, wvb, Vb, Dd, Dd);

  // 3. RoPE on Q and K
  rope_k<<<(Bb * Ss * Hh * 32) / 256, 256, 0, stream>>>(Qb);
  rope_k<<<(Bb * Ss * Hh * 32) / 256, 256, 0, stream>>>(Kb);

  // 4. V transpose -> [B,H,64,S]
  transpose_v<<<dim3(Ss / 64, Bb * Hh), 256, 0, stream>>>(Vb, Vt);

  // 5. causal flash attention -> [B,S,D] bf16
  attn_k<<<dim3(16, Bb * Hh), 256, 0, stream>>>(Qb, Kb, Vt, AOb);

  // 6. output projection (fp32 out)
  gemm_bt<float><<<gg, 256, 0, stream>>>(AOb, wob, out, Dd, Dd);
}